// Round 13
// baseline (468.917 us; speedup 1.0000x reference)
//
#include <hip/hip_runtime.h>
#include <stdint.h>

typedef __bf16 v8bf __attribute__((ext_vector_type(8)));
typedef float f32x4 __attribute__((ext_vector_type(4)));

__device__ __forceinline__ float b2f(unsigned short u) {
    unsigned int x = ((unsigned int)u) << 16;
    return __builtin_bit_cast(float, x);
}
__device__ __forceinline__ float b2f_lo(unsigned int v) {
    return __builtin_bit_cast(float, v << 16);
}
__device__ __forceinline__ float b2f_hi(unsigned int v) {
    return __builtin_bit_cast(float, v & 0xffff0000u);
}
__device__ __forceinline__ unsigned short f2b(float f) {
    unsigned int x = __builtin_bit_cast(unsigned int, f);
    unsigned int r = (x + 0x7fffu + ((x >> 16) & 1u)) >> 16;  // RNE
    return (unsigned short)r;
}

__device__ __forceinline__ void load_lds16(const void* g, void* l) {
    __builtin_amdgcn_global_load_lds(
        (__attribute__((address_space(1))) void*)(const void*)g,
        (__attribute__((address_space(3))) void*)l, 16, 0, 0);
}

// ---------------- weight conversion fp32 -> bf16 packed wbuf ----------------
struct WSrc { const float* p[7]; const float* s[6]; };

__global__ void k_cvtw(WSrc w, unsigned short* __restrict__ wbuf) {
    int idx = blockIdx.x * 256 + threadIdx.x;
    if (idx >= 115458) return;
    float v;
    if (idx < 114688) {
        v = w.p[idx >> 14][idx & 16383];
    } else {
        int rem = idx - 114688;
        int t, j;
        if (rem < 512)      { t = rem >> 7; j = rem & 127; }
        else if (rem < 768) { t = 4; j = rem - 512; }
        else                { t = 5; j = rem - 768; }
        v = w.s[t][j];
    }
    wbuf[idx] = f2b(v);
}

// ---------------- CSR build ----------------
__global__ void k_count(const int* __restrict__ dst, int* __restrict__ cnt, int E) {
    int i = blockIdx.x * 256 + threadIdx.x;
    if (i < E) atomicAdd(&cnt[dst[i]], 1);
}

__global__ void k_bsum(const int* __restrict__ cnt, int* __restrict__ bsum, int n) {
    __shared__ int s[256];
    int i = blockIdx.x * 256 + threadIdx.x;
    s[threadIdx.x] = (i < n) ? cnt[i] : 0;
    __syncthreads();
    for (int o = 128; o > 0; o >>= 1) {
        if (threadIdx.x < o) s[threadIdx.x] += s[threadIdx.x + o];
        __syncthreads();
    }
    if (threadIdx.x == 0) bsum[blockIdx.x] = s[0];
}

__global__ void k_scanb(const int* __restrict__ bsum, int* __restrict__ boff, int nb) {
    __shared__ int s[512];
    int t = threadIdx.x;
    int v0 = (t < nb) ? bsum[t] : 0;
    s[t] = v0;
    __syncthreads();
    for (int o = 1; o < 512; o <<= 1) {
        int v = (t >= o) ? s[t - o] : 0;
        __syncthreads();
        s[t] += v;
        __syncthreads();
    }
    if (t < nb) boff[t] = s[t] - v0;  // exclusive
}

__global__ void k_scanf(const int* __restrict__ cnt, const int* __restrict__ boff,
                        int* __restrict__ rs, int* __restrict__ pos,
                        float* __restrict__ inv, int n) {
    __shared__ int s[256];
    int t = threadIdx.x;
    int i = blockIdx.x * 256 + t;
    int c = (i < n) ? cnt[i] : 0;
    s[t] = c;
    __syncthreads();
    for (int o = 1; o < 256; o <<= 1) {
        int v = (t >= o) ? s[t - o] : 0;
        __syncthreads();
        s[t] += v;
        __syncthreads();
    }
    int start = boff[blockIdx.x] + s[t] - c;
    if (i < n) {
        rs[i] = start;
        pos[i] = start;
        inv[i] = 1.0f / (float)max(c, 1);
        if (i == n - 1) rs[n] = start + c;
    }
}

__global__ void k_fill(const int* __restrict__ src, const int* __restrict__ dst,
                       int* __restrict__ pos, int* __restrict__ csr, int E) {
    int i = blockIdx.x * 256 + threadIdx.x;
    if (i < E) {
        int p = atomicAdd(&pos[dst[i]], 1);
        csr[p] = src[i];
    }
}

// x (fp32 N x 128) -> bf16 xcat right half (stride 256)
__global__ void k_copyx(const float* __restrict__ x, unsigned short* __restrict__ xcat, int n) {
    int i = blockIdx.x * 256 + threadIdx.x;
    if (i < n * 32) {
        int row = i >> 5, c4 = (i & 31) * 4;
        float4 v = *(const float4*)&x[(size_t)row * 128 + c4];
        ushort4 o;
        o.x = f2b(v.x); o.y = f2b(v.y); o.z = f2b(v.z); o.w = f2b(v.w);
        *(ushort4*)&xcat[(size_t)row * 256 + 128 + c4] = o;
    }
}

// layer-0 mean-aggregate: 16-lane group per dst row, uint4/lane (8 feats).
__global__ __launch_bounds__(256) void k_agg(const unsigned short* __restrict__ xcat,
                                             const int* __restrict__ rs, const int* __restrict__ csr,
                                             const float* __restrict__ inv_cnt,
                                             unsigned short* __restrict__ outL, int n) {
    int t = threadIdx.x;
    int l = t & 15;                       // lane in group
    int gbase = (t & 63) & ~15;           // group's first lane within wave
    int d = blockIdx.x * 16 + (t >> 4);
    if (d >= n) return;
    int s = rs[d], e = rs[d + 1];
    int deg = e - s;
    float ax[8] = {};
    for (int base = 0; base < deg; base += 16) {
        int cnt16 = min(16, deg - base);
        int myidx = (base + l < deg) ? csr[s + base + l] : 0;
        for (int b = 0; b < cnt16; b += 8) {
            int idx[8];
            uint4 v[8];
#pragma unroll
            for (int u = 0; u < 8; u++) idx[u] = __shfl(myidx, gbase + b + u, 64);
#pragma unroll
            for (int u = 0; u < 8; u++)
                v[u] = *(const uint4*)&xcat[(size_t)idx[u] * 256 + 128 + l * 8];
#pragma unroll
            for (int u = 0; u < 8; u++) {
                float wgt = (b + u < cnt16) ? 1.f : 0.f;
                unsigned int uu[4] = {v[u].x, v[u].y, v[u].z, v[u].w};
#pragma unroll
                for (int k = 0; k < 4; k++) {
                    ax[2 * k]     += wgt * b2f_lo(uu[k]);
                    ax[2 * k + 1] += wgt * b2f_hi(uu[k]);
                }
            }
        }
    }
    float ic = inv_cnt[d];
    uint4 o;
    unsigned int* op = (unsigned int*)&o;
#pragma unroll
    for (int k = 0; k < 4; k++)
        op[k] = ((unsigned int)f2b(ax[2 * k + 1] * ic) << 16) | f2b(ax[2 * k] * ic);
    *(uint4*)&outL[(size_t)d * 256 + l * 8] = o;
}

// fused BN(stat-reduce)+ReLU+mean-aggregate, 16-lane-group version.
__global__ __launch_bounds__(256) void k_aggbn(const unsigned short* __restrict__ Y,
                                               const float* __restrict__ statp,
                                               const int* __restrict__ rs, const int* __restrict__ csr,
                                               const float* __restrict__ inv_cnt,
                                               unsigned short* __restrict__ xcat, int n, float invN) {
    __shared__ float smu[128], sinv[128];
    int t = threadIdx.x;
    if (t < 128) {
        float s = 0.f, q = 0.f;
#pragma unroll
        for (int sl = 0; sl < 32; sl++) {
            s += statp[sl * 256 + t];
            q += statp[sl * 256 + 128 + t];
        }
        float mu = s * invN;
        float var = q * invN - mu * mu;
        smu[t] = mu;
        sinv[t] = rsqrtf(var + 1e-5f);
    }
    __syncthreads();
    int l = t & 15;
    int gbase = (t & 63) & ~15;
    int d = blockIdx.x * 16 + (t >> 4);
    if (d >= n) return;
    float mu[8], iv[8];
#pragma unroll
    for (int k = 0; k < 8; k++) { mu[k] = smu[l * 8 + k]; iv[k] = sinv[l * 8 + k]; }
    // own row -> xcat right half
    {
        uint4 vo = *(const uint4*)&Y[(size_t)d * 128 + l * 8];
        unsigned int uu[4] = {vo.x, vo.y, vo.z, vo.w};
        uint4 o;
        unsigned int* op = (unsigned int*)&o;
#pragma unroll
        for (int k = 0; k < 4; k++) {
            float a = fmaxf((b2f_lo(uu[k]) - mu[2 * k]) * iv[2 * k], 0.f);
            float b = fmaxf((b2f_hi(uu[k]) - mu[2 * k + 1]) * iv[2 * k + 1], 0.f);
            op[k] = ((unsigned int)f2b(b) << 16) | f2b(a);
        }
        *(uint4*)&xcat[(size_t)d * 256 + 128 + l * 8] = o;
    }
    // gather neighbors from raw Y, BN+ReLU per value
    int s = rs[d], e = rs[d + 1];
    int deg = e - s;
    float ax[8] = {};
    for (int base = 0; base < deg; base += 16) {
        int cnt16 = min(16, deg - base);
        int myidx = (base + l < deg) ? csr[s + base + l] : 0;
        for (int b = 0; b < cnt16; b += 8) {
            int idx[8];
            uint4 v[8];
#pragma unroll
            for (int u = 0; u < 8; u++) idx[u] = __shfl(myidx, gbase + b + u, 64);
#pragma unroll
            for (int u = 0; u < 8; u++)
                v[u] = *(const uint4*)&Y[(size_t)idx[u] * 128 + l * 8];
#pragma unroll
            for (int u = 0; u < 8; u++) {
                float wgt = (b + u < cnt16) ? 1.f : 0.f;
                unsigned int uu[4] = {v[u].x, v[u].y, v[u].z, v[u].w};
#pragma unroll
                for (int k = 0; k < 4; k++) {
                    ax[2 * k]     += wgt * fmaxf((b2f_lo(uu[k]) - mu[2 * k]) * iv[2 * k], 0.f);
                    ax[2 * k + 1] += wgt * fmaxf((b2f_hi(uu[k]) - mu[2 * k + 1]) * iv[2 * k + 1], 0.f);
                }
            }
        }
    }
    float ic = inv_cnt[d];
    uint4 o;
    unsigned int* op = (unsigned int*)&o;
#pragma unroll
    for (int k = 0; k < 4; k++)
        op[k] = ((unsigned int)f2b(ax[2 * k + 1] * ic) << 16) | f2b(ax[2 * k] * ic);
    *(uint4*)&xcat[(size_t)d * 256 + l * 8] = o;
}

// Barrier-free W-resident persistent GEMM: W (128 x K) staged to LDS once
// (single barrier); A fragments loaded per-lane global->VGPR (quads of one
// row cover one 64B line; 4 waves share the tile via L1). No K-loop barriers:
// compiler interleaves global loads with MFMA via vmcnt. Grid-stride M-tiles.
__global__ __launch_bounds__(256, 4) void k_wgemm(const unsigned short* __restrict__ A, int lda, int aoff,
                                                  const unsigned short* __restrict__ W0,
                                                  const unsigned short* __restrict__ W1,
                                                  const unsigned short* __restrict__ bias,
                                                  unsigned short* __restrict__ Y,
                                                  float* __restrict__ statp, int nrows, int K) {
    __shared__ __align__(16) unsigned short Ws[8][4096];  // 64 KB (K=256); K=128 uses half
    int t = threadIdx.x;
    int wv = t >> 6, lane = t & 63;
    int quad = lane >> 4, l16 = lane & 15;
    const int nchunks = K >> 5;

    // ---- W prologue: stage all chunks once ----
    for (int c = 0; c < nchunks; c++) {
        const unsigned short* Wp = (c < 4) ? W0 : W1;
        int wkc = (c & 3) * 32;
#pragma unroll
        for (int q = 0; q < 2; q++) {
            int r = q * 64 + (t >> 2);
            load_lds16(Wp + (size_t)r * 128 + wkc + (t & 3) * 8,
                       &Ws[c][(size_t)r * 32 + (t & 3) * 8]);
        }
    }
    __syncthreads();   // only barrier: W resident + read-only from here on

    // bias per lane (cols fixed): c0(j) = wv*32 + j*16 + quad*4
    float bn[2][4];
#pragma unroll
    for (int j = 0; j < 2; j++) {
        int c0 = wv * 32 + j * 16 + quad * 4;
        uint2 bu = *(const uint2*)&bias[c0];
        bn[j][0] = b2f_lo(bu.x); bn[j][1] = b2f_hi(bu.x);
        bn[j][2] = b2f_lo(bu.y); bn[j][3] = b2f_hi(bu.y);
    }

    f32x4 cs_[2] = {}, cq_[2] = {};   // running stats per j (4 cols each)
    int ntiles = (nrows + 31) >> 5;

    for (int mt = blockIdx.x; mt < ntiles; mt += gridDim.x) {
        int m0 = mt * 32;
        int r0 = m0 + l16;       if (r0 >= nrows) r0 = nrows - 1;
        int r1 = m0 + 16 + l16;  if (r1 >= nrows) r1 = nrows - 1;
        const unsigned short* a0 = A + (size_t)r0 * lda + aoff + quad * 8;
        const unsigned short* a1 = A + (size_t)r1 * lda + aoff + quad * 8;

        f32x4 acc[2][2] = {};
#pragma unroll
        for (int ch = 0; ch < 8; ch++) {
            if (ch >= nchunks) break;
            v8bf af0 = *(const v8bf*)(a0 + ch * 32);
            v8bf af1 = *(const v8bf*)(a1 + ch * 32);
            v8bf b0 = *(const v8bf*)&Ws[ch][(wv * 32 + l16) * 32 + quad * 8];
            v8bf b1 = *(const v8bf*)&Ws[ch][(wv * 32 + 16 + l16) * 32 + quad * 8];
            acc[0][0] = __builtin_amdgcn_mfma_f32_16x16x32_bf16(b0, af0, acc[0][0], 0, 0, 0);
            acc[0][1] = __builtin_amdgcn_mfma_f32_16x16x32_bf16(b1, af0, acc[0][1], 0, 0, 0);
            acc[1][0] = __builtin_amdgcn_mfma_f32_16x16x32_bf16(b0, af1, acc[1][0], 0, 0, 0);
            acc[1][1] = __builtin_amdgcn_mfma_f32_16x16x32_bf16(b1, af1, acc[1][1], 0, 0, 0);
        }

        // bias into acc, tight store, stats accumulate
#pragma unroll
        for (int i = 0; i < 2; i++)
#pragma unroll
            for (int j = 0; j < 2; j++)
#pragma unroll
                for (int u = 0; u < 4; u++)
                    acc[i][j][u] += bn[j][u];
#pragma unroll
        for (int i = 0; i < 2; i++) {
            int row = m0 + i * 16 + l16;
            if (row < nrows) {
#pragma unroll
                for (int j = 0; j < 2; j++) {
                    int c0 = wv * 32 + j * 16 + quad * 4;
                    uint2 o;
                    o.x = ((unsigned int)f2b(acc[i][j][1]) << 16) | f2b(acc[i][j][0]);
                    o.y = ((unsigned int)f2b(acc[i][j][3]) << 16) | f2b(acc[i][j][2]);
                    *(uint2*)&Y[(size_t)row * 128 + c0] = o;
                }
            }
        }
#pragma unroll
        for (int i = 0; i < 2; i++) {
            int row = m0 + i * 16 + l16;
            if (row < nrows) {
#pragma unroll
                for (int j = 0; j < 2; j++)
#pragma unroll
                    for (int u = 0; u < 4; u++) {
                        float v = acc[i][j][u];
                        cs_[j][u] += v;
                        cq_[j][u] += v * v;
                    }
            }
        }
    }

    // final stats reduce (over 16-lane row group) + one atomic set per block
    float* sp = statp + (blockIdx.x & 31) * 256;
#pragma unroll
    for (int j = 0; j < 2; j++) {
        for (int m = 1; m < 16; m <<= 1) {
#pragma unroll
            for (int u = 0; u < 4; u++) {
                cs_[j][u] += __shfl_xor(cs_[j][u], m, 64);
                cq_[j][u] += __shfl_xor(cq_[j][u], m, 64);
            }
        }
        if (l16 == 0) {
            int c0 = wv * 32 + j * 16 + quad * 4;
#pragma unroll
            for (int u = 0; u < 4; u++) {
                atomicAdd(&sp[c0 + u], cs_[j][u]);
                atomicAdd(&sp[128 + c0 + u], cq_[j][u]);
            }
        }
    }
}

// BN(stat-reduce) + ReLU + bf16 pack (MLP stage); uint4 (8 feats/thread)
__global__ __launch_bounds__(256) void k_bnrelu(const unsigned short* __restrict__ Y,
                                                const float* __restrict__ statp,
                                                unsigned short* __restrict__ out, int ldo,
                                                int n, float invN) {
    __shared__ float smu[128], sinv[128];
    int t = threadIdx.x;
    if (t < 128) {
        float s = 0.f, q = 0.f;
#pragma unroll
        for (int sl = 0; sl < 32; sl++) {
            s += statp[sl * 256 + t];
            q += statp[sl * 256 + 128 + t];
        }
        float mu = s * invN;
        float var = q * invN - mu * mu;
        smu[t] = mu;
        sinv[t] = rsqrtf(var + 1e-5f);
    }
    __syncthreads();
    int i = blockIdx.x * 256 + t;
    if (i >= n * 16) return;
    int row = i >> 4, f8 = (i & 15) * 8;
    uint4 v = *(const uint4*)&Y[(size_t)row * 128 + f8];
    unsigned int u[4] = {v.x, v.y, v.z, v.w};
    uint4 o;
    unsigned int* op = (unsigned int*)&o;
    for (int k = 0; k < 4; k++) {
        int f = f8 + k * 2;
        float a = fmaxf((b2f_lo(u[k]) - smu[f]) * sinv[f], 0.f);
        float b = fmaxf((b2f_hi(u[k]) - smu[f + 1]) * sinv[f + 1], 0.f);
        op[k] = ((unsigned int)f2b(b) << 16) | f2b(a);
    }
    *(uint4*)&out[(size_t)row * ldo + f8] = o;
}

// layer-4 BN(stat-reduce) + ReLU + final 128->2 projection; wave per row, fp32 out
__global__ __launch_bounds__(256) void k_bnfinal(const unsigned short* __restrict__ Y,
                                                 const float* __restrict__ statp,
                                                 const unsigned short* __restrict__ W2,
                                                 const unsigned short* __restrict__ b2v,
                                                 float* __restrict__ out, int n, float invN) {
    __shared__ float smu[128], sinv[128];
    int t = threadIdx.x;
    if (t < 128) {
        float s = 0.f, q = 0.f;
#pragma unroll
        for (int sl = 0; sl < 32; sl++) {
            s += statp[sl * 256 + t];
            q += statp[sl * 256 + 128 + t];
        }
        float mu = s * invN;
        float var = q * invN - mu * mu;
        smu[t] = mu;
        sinv[t] = rsqrtf(var + 1e-5f);
    }
    __syncthreads();
    int wid = t >> 6, lane = t & 63;
    int r = blockIdx.x * 4 + wid;
    if (r >= n) return;
    int f2 = lane * 2;
    unsigned int v = *(const unsigned int*)&Y[(size_t)r * 128 + f2];
    float a = fmaxf((b2f_lo(v) - smu[f2]) * sinv[f2], 0.f);
    float b = fmaxf((b2f_hi(v) - smu[f2 + 1]) * sinv[f2 + 1], 0.f);
    unsigned int w0 = *(const unsigned int*)&W2[f2];
    unsigned int w1 = *(const unsigned int*)&W2[128 + f2];
    float d0 = a * b2f_lo(w0) + b * b2f_hi(w0);
    float d1 = a * b2f_lo(w1) + b * b2f_hi(w1);
    for (int o = 32; o > 0; o >>= 1) {
        d0 += __shfl_down(d0, o, 64);
        d1 += __shfl_down(d1, o, 64);
    }
    if (lane == 0) {
        float2 o2;
        o2.x = d0 + b2f(b2v[0]);
        o2.y = d1 + b2f(b2v[1]);
        *(float2*)&out[(size_t)r * 2] = o2;
    }
}

extern "C" void kernel_launch(void* const* d_in, const int* in_sizes, int n_in,
                              void* d_out, int out_size, void* d_ws, size_t ws_size,
                              hipStream_t stream) {
    const int N = in_sizes[0] / 128;
    const int E = in_sizes[1] / 2;

    const float* x = (const float*)d_in[0];
    const int* ei = (const int*)d_in[1];
    const int* srcp = ei;
    const int* dstp = ei + E;
    float* out = (float*)d_out;

    char* w = (char*)d_ws;
    auto align256 = [](size_t v) { return (v + 255) & ~(size_t)255; };
    size_t o_xcat = 0;
    size_t o_y    = align256(o_xcat + (size_t)N * 256 * 2);
    size_t o_csr  = align256(o_y + (size_t)N * 128 * 2);
    size_t o_rs   = align256(o_csr + (size_t)E * 4);
    size_t o_pos  = align256(o_rs + (size_t)(N + 1) * 4);
    size_t o_inv  = align256(o_pos + (size_t)N * 4);
    size_t o_cnt  = align256(o_inv + (size_t)N * 4);
    size_t o_stat = o_cnt + (size_t)N * 4;            // contiguous with cnt (one memset)
    size_t o_bsum = align256(o_stat + 4 * 8192 * 4);
    size_t o_boff = align256(o_bsum + 1024 * 4);
    size_t o_wbuf = align256(o_boff + 1024 * 4);

    unsigned short* xcat = (unsigned short*)(w + o_xcat);
    unsigned short* y    = (unsigned short*)(w + o_y);
    int* csr = (int*)(w + o_csr);
    int* rs  = (int*)(w + o_rs);
    int* pos = (int*)(w + o_pos);
    float* inv = (float*)(w + o_inv);
    int* cnt = (int*)(w + o_cnt);
    float* stat = (float*)(w + o_stat);
    int* bsum = (int*)(w + o_bsum);
    int* boff = (int*)(w + o_boff);
    unsigned short* wbuf = (unsigned short*)(w + o_wbuf);

    const unsigned short* Wl[3] = {wbuf + 0,      wbuf + 32768, wbuf + 65536};
    const unsigned short* Wr[3] = {wbuf + 16384,  wbuf + 49152, wbuf + 81920};
    const unsigned short* W1b   = wbuf + 98304;
    const unsigned short* bl[3] = {wbuf + 114688, wbuf + 114816, wbuf + 114944};
    const unsigned short* b1b   = wbuf + 115072;
    const unsigned short* W2b   = wbuf + 115200;
    const unsigned short* b2b   = wbuf + 115456;

    WSrc wsrc;
    wsrc.p[0] = (const float*)d_in[2];   // Wl0
    wsrc.p[1] = (const float*)d_in[4];   // Wr0
    wsrc.p[2] = (const float*)d_in[5];   // Wl1
    wsrc.p[3] = (const float*)d_in[7];   // Wr1
    wsrc.p[4] = (const float*)d_in[8];   // Wl2
    wsrc.p[5] = (const float*)d_in[10];  // Wr2
    wsrc.p[6] = (const float*)d_in[11];  // W1
    wsrc.s[0] = (const float*)d_in[3];   // bl0
    wsrc.s[1] = (const float*)d_in[6];   // bl1
    wsrc.s[2] = (const float*)d_in[9];   // bl2
    wsrc.s[3] = (const float*)d_in[12];  // b1
    wsrc.s[4] = (const float*)d_in[13];  // W2
    wsrc.s[5] = (const float*)d_in[14];  // b2

    const int NB = (N + 255) / 256;

    // zero cnt + stat (contiguous, one memset)
    hipMemsetAsync(w + o_cnt, 0, (size_t)N * 4 + 4 * 8192 * 4, stream);

    k_cvtw<<<(115458 + 255) / 256, 256, 0, stream>>>(wsrc, wbuf);
    k_count<<<(E + 255) / 256, 256, 0, stream>>>(dstp, cnt, E);
    k_bsum<<<NB, 256, 0, stream>>>(cnt, bsum, N);
    k_scanb<<<1, 512, 0, stream>>>(bsum, boff, NB);
    k_scanf<<<NB, 256, 0, stream>>>(cnt, boff, rs, pos, inv, N);
    k_fill<<<(E + 255) / 256, 256, 0, stream>>>(srcp, dstp, pos, csr, E);
    k_copyx<<<(N * 32 + 255) / 256, 256, 0, stream>>>(x, xcat, N);

    const int wg_grid = 512;     // persistent: 2 blocks/CU
    const int agg16_grid = (N + 15) / 16;
    const int wave_grid = (N + 3) / 4;
    const int bnr_grid = (N * 16 + 255) / 256;
    const float invN = 1.0f / (float)N;

    // layer 0
    k_agg<<<agg16_grid, 256, 0, stream>>>(xcat, rs, csr, inv, xcat, N);
    k_wgemm<<<wg_grid, 256, 0, stream>>>(xcat, 256, 0, Wl[0], Wr[0], bl[0], y, stat + 0 * 8192, N, 256);
    // layers 1,2: fused BN+ReLU+agg from raw Y
    for (int i = 1; i < 3; i++) {
        k_aggbn<<<agg16_grid, 256, 0, stream>>>(y, stat + (i - 1) * 8192, rs, csr, inv, xcat, N, invN);
        k_wgemm<<<wg_grid, 256, 0, stream>>>(xcat, 256, 0, Wl[i], Wr[i], bl[i], y, stat + i * 8192, N, 256);
    }
    // MLP stage: BN+ReLU -> xcatR, then K=128 gemm
    k_bnrelu<<<bnr_grid, 256, 0, stream>>>(y, stat + 2 * 8192, xcat + 128, 256, N, invN);
    k_wgemm<<<wg_grid, 256, 0, stream>>>(xcat, 256, 128, W1b, W1b, b1b, y, stat + 3 * 8192, N, 128);
    k_bnfinal<<<wave_grid, 256, 0, stream>>>(y, stat + 3 * 8192, W2b, b2b, out, N, invN);
}

// Round 14
// 417.450 us; speedup vs baseline: 1.1233x; 1.1233x over previous
//
#include <hip/hip_runtime.h>
#include <stdint.h>

typedef __bf16 v8bf __attribute__((ext_vector_type(8)));
typedef float f32x4 __attribute__((ext_vector_type(4)));

__device__ __forceinline__ float b2f(unsigned short u) {
    unsigned int x = ((unsigned int)u) << 16;
    return __builtin_bit_cast(float, x);
}
__device__ __forceinline__ float b2f_lo(unsigned int v) {
    return __builtin_bit_cast(float, v << 16);
}
__device__ __forceinline__ float b2f_hi(unsigned int v) {
    return __builtin_bit_cast(float, v & 0xffff0000u);
}
__device__ __forceinline__ unsigned short f2b(float f) {
    unsigned int x = __builtin_bit_cast(unsigned int, f);
    unsigned int r = (x + 0x7fffu + ((x >> 16) & 1u)) >> 16;  // RNE
    return (unsigned short)r;
}

__device__ __forceinline__ void load_lds16(const void* g, void* l) {
    __builtin_amdgcn_global_load_lds(
        (__attribute__((address_space(1))) void*)(const void*)g,
        (__attribute__((address_space(3))) void*)l, 16, 0, 0);
}

// ---------------- fused prologue: cvtw + edge-count + copyx ----------------
// wbuf layout (bf16 elements):
//   Wl0:0  Wr0:16384  Wl1:32768  Wr1:49152  Wl2:65536  Wr2:81920  W1:98304
//   bl0:114688 bl1:114816 bl2:114944 b1:115072 W2:115200 b2:115456
struct WSrc { const float* p[7]; const float* s[6]; };

__global__ void k_prologue(WSrc w, unsigned short* __restrict__ wbuf,
                           const int* __restrict__ dst, int* __restrict__ cnt, int E,
                           const float* __restrict__ x, unsigned short* __restrict__ xcat,
                           int n, int nCvtw, int nCount) {
    int bid = blockIdx.x;
    int t = threadIdx.x;
    if (bid < nCvtw) {
        int idx = bid * 256 + t;
        if (idx >= 115458) return;
        float v;
        if (idx < 114688) {
            v = w.p[idx >> 14][idx & 16383];
        } else {
            int rem = idx - 114688;
            int tt, j;
            if (rem < 512)      { tt = rem >> 7; j = rem & 127; }
            else if (rem < 768) { tt = 4; j = rem - 512; }
            else                { tt = 5; j = rem - 768; }
            v = w.s[tt][j];
        }
        wbuf[idx] = f2b(v);
    } else if (bid < nCvtw + nCount) {
        int i = (bid - nCvtw) * 256 + t;
        if (i < E) atomicAdd(&cnt[dst[i]], 1);
    } else {
        int i = (bid - nCvtw - nCount) * 256 + t;
        if (i < n * 32) {
            int row = i >> 5, c4 = (i & 31) * 4;
            float4 v = *(const float4*)&x[(size_t)row * 128 + c4];
            ushort4 o;
            o.x = f2b(v.x); o.y = f2b(v.y); o.z = f2b(v.z); o.w = f2b(v.w);
            *(ushort4*)&xcat[(size_t)row * 256 + 128 + c4] = o;
        }
    }
}

// ---------------- CSR build (scan chain) ----------------
__global__ void k_bsum(const int* __restrict__ cnt, int* __restrict__ bsum, int n) {
    __shared__ int s[256];
    int i = blockIdx.x * 256 + threadIdx.x;
    s[threadIdx.x] = (i < n) ? cnt[i] : 0;
    __syncthreads();
    for (int o = 128; o > 0; o >>= 1) {
        if (threadIdx.x < o) s[threadIdx.x] += s[threadIdx.x + o];
        __syncthreads();
    }
    if (threadIdx.x == 0) bsum[blockIdx.x] = s[0];
}

__global__ void k_scanb(const int* __restrict__ bsum, int* __restrict__ boff, int nb) {
    __shared__ int s[512];
    int t = threadIdx.x;
    int v0 = (t < nb) ? bsum[t] : 0;
    s[t] = v0;
    __syncthreads();
    for (int o = 1; o < 512; o <<= 1) {
        int v = (t >= o) ? s[t - o] : 0;
        __syncthreads();
        s[t] += v;
        __syncthreads();
    }
    if (t < nb) boff[t] = s[t] - v0;  // exclusive
}

__global__ void k_scanf(const int* __restrict__ cnt, const int* __restrict__ boff,
                        int* __restrict__ rs, int* __restrict__ pos,
                        float* __restrict__ inv, int n) {
    __shared__ int s[256];
    int t = threadIdx.x;
    int i = blockIdx.x * 256 + t;
    int c = (i < n) ? cnt[i] : 0;
    s[t] = c;
    __syncthreads();
    for (int o = 1; o < 256; o <<= 1) {
        int v = (t >= o) ? s[t - o] : 0;
        __syncthreads();
        s[t] += v;
        __syncthreads();
    }
    int start = boff[blockIdx.x] + s[t] - c;
    if (i < n) {
        rs[i] = start;
        pos[i] = start;
        inv[i] = 1.0f / (float)max(c, 1);
        if (i == n - 1) rs[n] = start + c;
    }
}

__global__ void k_fill(const int* __restrict__ src, const int* __restrict__ dst,
                       int* __restrict__ pos, int* __restrict__ csr, int E) {
    int i = blockIdx.x * 256 + threadIdx.x;
    if (i < E) {
        int p = atomicAdd(&pos[dst[i]], 1);
        csr[p] = src[i];
    }
}

// layer-0 mean-aggregate: 16-lane group per dst row, uint4/lane (8 feats).
__global__ __launch_bounds__(256) void k_agg(const unsigned short* __restrict__ xcat,
                                             const int* __restrict__ rs, const int* __restrict__ csr,
                                             const float* __restrict__ inv_cnt,
                                             unsigned short* __restrict__ outL, int n) {
    int t = threadIdx.x;
    int l = t & 15;                       // lane in group
    int gbase = (t & 63) & ~15;           // group's first lane within wave
    int d = blockIdx.x * 16 + (t >> 4);
    if (d >= n) return;
    int s = rs[d], e = rs[d + 1];
    int deg = e - s;
    float ax[8] = {};
    for (int base = 0; base < deg; base += 16) {
        int cnt16 = min(16, deg - base);
        int myidx = (base + l < deg) ? csr[s + base + l] : 0;
        for (int b = 0; b < cnt16; b += 8) {
            int idx[8];
            uint4 v[8];
#pragma unroll
            for (int u = 0; u < 8; u++) idx[u] = __shfl(myidx, gbase + b + u, 64);
#pragma unroll
            for (int u = 0; u < 8; u++)
                v[u] = *(const uint4*)&xcat[(size_t)idx[u] * 256 + 128 + l * 8];
#pragma unroll
            for (int u = 0; u < 8; u++) {
                float wgt = (b + u < cnt16) ? 1.f : 0.f;
                unsigned int uu[4] = {v[u].x, v[u].y, v[u].z, v[u].w};
#pragma unroll
                for (int k = 0; k < 4; k++) {
                    ax[2 * k]     += wgt * b2f_lo(uu[k]);
                    ax[2 * k + 1] += wgt * b2f_hi(uu[k]);
                }
            }
        }
    }
    float ic = inv_cnt[d];
    uint4 o;
    unsigned int* op = (unsigned int*)&o;
#pragma unroll
    for (int k = 0; k < 4; k++)
        op[k] = ((unsigned int)f2b(ax[2 * k + 1] * ic) << 16) | f2b(ax[2 * k] * ic);
    *(uint4*)&outL[(size_t)d * 256 + l * 8] = o;
}

// fused BN(stat-reduce)+ReLU+mean-aggregate, 16-lane-group version.
__global__ __launch_bounds__(256) void k_aggbn(const unsigned short* __restrict__ Y,
                                               const float* __restrict__ statp,
                                               const int* __restrict__ rs, const int* __restrict__ csr,
                                               const float* __restrict__ inv_cnt,
                                               unsigned short* __restrict__ xcat, int n, float invN) {
    __shared__ float smu[128], sinv[128];
    int t = threadIdx.x;
    if (t < 128) {
        float s = 0.f, q = 0.f;
#pragma unroll
        for (int sl = 0; sl < 32; sl++) {
            s += statp[sl * 256 + t];
            q += statp[sl * 256 + 128 + t];
        }
        float mu = s * invN;
        float var = q * invN - mu * mu;
        smu[t] = mu;
        sinv[t] = rsqrtf(var + 1e-5f);
    }
    __syncthreads();
    int l = t & 15;
    int gbase = (t & 63) & ~15;
    int d = blockIdx.x * 16 + (t >> 4);
    if (d >= n) return;
    float mu[8], iv[8];
#pragma unroll
    for (int k = 0; k < 8; k++) { mu[k] = smu[l * 8 + k]; iv[k] = sinv[l * 8 + k]; }
    // own row -> xcat right half
    {
        uint4 vo = *(const uint4*)&Y[(size_t)d * 128 + l * 8];
        unsigned int uu[4] = {vo.x, vo.y, vo.z, vo.w};
        uint4 o;
        unsigned int* op = (unsigned int*)&o;
#pragma unroll
        for (int k = 0; k < 4; k++) {
            float a = fmaxf((b2f_lo(uu[k]) - mu[2 * k]) * iv[2 * k], 0.f);
            float b = fmaxf((b2f_hi(uu[k]) - mu[2 * k + 1]) * iv[2 * k + 1], 0.f);
            op[k] = ((unsigned int)f2b(b) << 16) | f2b(a);
        }
        *(uint4*)&xcat[(size_t)d * 256 + 128 + l * 8] = o;
    }
    // gather neighbors from raw Y, BN+ReLU per value
    int s = rs[d], e = rs[d + 1];
    int deg = e - s;
    float ax[8] = {};
    for (int base = 0; base < deg; base += 16) {
        int cnt16 = min(16, deg - base);
        int myidx = (base + l < deg) ? csr[s + base + l] : 0;
        for (int b = 0; b < cnt16; b += 8) {
            int idx[8];
            uint4 v[8];
#pragma unroll
            for (int u = 0; u < 8; u++) idx[u] = __shfl(myidx, gbase + b + u, 64);
#pragma unroll
            for (int u = 0; u < 8; u++)
                v[u] = *(const uint4*)&Y[(size_t)idx[u] * 128 + l * 8];
#pragma unroll
            for (int u = 0; u < 8; u++) {
                float wgt = (b + u < cnt16) ? 1.f : 0.f;
                unsigned int uu[4] = {v[u].x, v[u].y, v[u].z, v[u].w};
#pragma unroll
                for (int k = 0; k < 4; k++) {
                    ax[2 * k]     += wgt * fmaxf((b2f_lo(uu[k]) - mu[2 * k]) * iv[2 * k], 0.f);
                    ax[2 * k + 1] += wgt * fmaxf((b2f_hi(uu[k]) - mu[2 * k + 1]) * iv[2 * k + 1], 0.f);
                }
            }
        }
    }
    float ic = inv_cnt[d];
    uint4 o;
    unsigned int* op = (unsigned int*)&o;
#pragma unroll
    for (int k = 0; k < 4; k++)
        op[k] = ((unsigned int)f2b(ax[2 * k + 1] * ic) << 16) | f2b(ax[2 * k] * ic);
    *(uint4*)&xcat[(size_t)d * 256 + l * 8] = o;
}

// W-resident persistent GEMM (R12 version): W (128 x K) loaded to LDS once per
// block; grid-stride over 32-row M-tiles. C = A @ W^T + bias, fused stats.
__global__ __launch_bounds__(256) void k_wgemm(const unsigned short* __restrict__ A, int lda, int aoff,
                                               const unsigned short* __restrict__ W0,
                                               const unsigned short* __restrict__ W1,
                                               const unsigned short* __restrict__ bias,
                                               unsigned short* __restrict__ Y,
                                               float* __restrict__ statp, int nrows, int K) {
    __shared__ __align__(16) unsigned short Ws[8][4096];  // 64 KB: 8 chunks of 128x32
    __shared__ __align__(16) unsigned short As[8][1024];  // 16 KB: 8 chunks of 32x32
    int t = threadIdx.x;
    int wv = t >> 6, lane = t & 63;
    int quad = lane >> 4, l16 = lane & 15;
    const int nchunks = K >> 5;

    // ---- W prologue: stage all chunks once (lane-linear LDS) ----
    for (int c = 0; c < nchunks; c++) {
        const unsigned short* Wp = (c < 4) ? W0 : W1;
        int wkc = (c & 3) * 32;
#pragma unroll
        for (int q = 0; q < 2; q++) {
            int r = q * 64 + (t >> 2);
            load_lds16(Wp + (size_t)r * 128 + wkc + (t & 3) * 8,
                       &Ws[c][(size_t)r * 32 + (t & 3) * 8]);
        }
    }

    // bias per lane (cols fixed): c0(j) = wv*32 + j*16 + quad*4
    float bn[2][4];
#pragma unroll
    for (int j = 0; j < 2; j++) {
        int c0 = wv * 32 + j * 16 + quad * 4;
        uint2 bu = *(const uint2*)&bias[c0];
        bn[j][0] = b2f_lo(bu.x); bn[j][1] = b2f_hi(bu.x);
        bn[j][2] = b2f_lo(bu.y); bn[j][3] = b2f_hi(bu.y);
    }

    f32x4 cs_[2] = {}, cq_[2] = {};   // running stats per j (4 cols each)

    int ntiles = (nrows + 31) >> 5;
    int tt = t & 127;
    int half = t >> 7;
    int ar = tt >> 2, ac = (tt & 3) * 8;

    for (int mt = blockIdx.x; mt < ntiles; mt += gridDim.x) {
        int m0 = mt * 32;
        __syncthreads();   // As free (prev tile's MFMA reads done)
        for (int pass = 0; pass < (nchunks >> 1); pass++) {
            int ch = pass * 2 + half;
            int gr = m0 + ar;
            if (gr >= nrows) gr = nrows - 1;
            load_lds16(A + (size_t)gr * lda + aoff + ch * 32 + ac,
                       &As[ch][(size_t)ar * 32 + ac]);
        }
        __syncthreads();   // As (and first-iter W) ready

        f32x4 acc[2][2] = {};
        for (int ch = 0; ch < nchunks; ch++) {
            v8bf af[2], bfv[2];
#pragma unroll
            for (int i = 0; i < 2; i++)
                af[i] = *(const v8bf*)&As[ch][(i * 16 + l16) * 32 + quad * 8];
#pragma unroll
            for (int j = 0; j < 2; j++)
                bfv[j] = *(const v8bf*)&Ws[ch][(wv * 32 + j * 16 + l16) * 32 + quad * 8];
#pragma unroll
            for (int i = 0; i < 2; i++)
#pragma unroll
                for (int j = 0; j < 2; j++)
                    acc[i][j] = __builtin_amdgcn_mfma_f32_16x16x32_bf16(bfv[j], af[i], acc[i][j], 0, 0, 0);
        }

        // bias into acc, tight store, stats accumulate
#pragma unroll
        for (int i = 0; i < 2; i++)
#pragma unroll
            for (int j = 0; j < 2; j++)
#pragma unroll
                for (int u = 0; u < 4; u++)
                    acc[i][j][u] += bn[j][u];
#pragma unroll
        for (int i = 0; i < 2; i++) {
            int row = m0 + i * 16 + l16;
            if (row < nrows) {
#pragma unroll
                for (int j = 0; j < 2; j++) {
                    int c0 = wv * 32 + j * 16 + quad * 4;
                    uint2 o;
                    o.x = ((unsigned int)f2b(acc[i][j][1]) << 16) | f2b(acc[i][j][0]);
                    o.y = ((unsigned int)f2b(acc[i][j][3]) << 16) | f2b(acc[i][j][2]);
                    *(uint2*)&Y[(size_t)row * 128 + c0] = o;
                }
            }
        }
#pragma unroll
        for (int i = 0; i < 2; i++) {
            int row = m0 + i * 16 + l16;
            if (row < nrows) {
#pragma unroll
                for (int j = 0; j < 2; j++)
#pragma unroll
                    for (int u = 0; u < 4; u++) {
                        float v = acc[i][j][u];
                        cs_[j][u] += v;
                        cq_[j][u] += v * v;
                    }
            }
        }
    }

    // final stats reduce (over 16-lane row group) + one atomic set per block
    float* sp = statp + (blockIdx.x & 31) * 256;
#pragma unroll
    for (int j = 0; j < 2; j++) {
        for (int m = 1; m < 16; m <<= 1) {
#pragma unroll
            for (int u = 0; u < 4; u++) {
                cs_[j][u] += __shfl_xor(cs_[j][u], m, 64);
                cq_[j][u] += __shfl_xor(cq_[j][u], m, 64);
            }
        }
        if (l16 == 0) {
            int c0 = wv * 32 + j * 16 + quad * 4;
#pragma unroll
            for (int u = 0; u < 4; u++) {
                atomicAdd(&sp[c0 + u], cs_[j][u]);
                atomicAdd(&sp[128 + c0 + u], cq_[j][u]);
            }
        }
    }
}

// BN(stat-reduce) + ReLU + bf16 pack (MLP stage); uint4 (8 feats/thread)
__global__ __launch_bounds__(256) void k_bnrelu(const unsigned short* __restrict__ Y,
                                                const float* __restrict__ statp,
                                                unsigned short* __restrict__ out, int ldo,
                                                int n, float invN) {
    __shared__ float smu[128], sinv[128];
    int t = threadIdx.x;
    if (t < 128) {
        float s = 0.f, q = 0.f;
#pragma unroll
        for (int sl = 0; sl < 32; sl++) {
            s += statp[sl * 256 + t];
            q += statp[sl * 256 + 128 + t];
        }
        float mu = s * invN;
        float var = q * invN - mu * mu;
        smu[t] = mu;
        sinv[t] = rsqrtf(var + 1e-5f);
    }
    __syncthreads();
    int i = blockIdx.x * 256 + t;
    if (i >= n * 16) return;
    int row = i >> 4, f8 = (i & 15) * 8;
    uint4 v = *(const uint4*)&Y[(size_t)row * 128 + f8];
    unsigned int u[4] = {v.x, v.y, v.z, v.w};
    uint4 o;
    unsigned int* op = (unsigned int*)&o;
    for (int k = 0; k < 4; k++) {
        int f = f8 + k * 2;
        float a = fmaxf((b2f_lo(u[k]) - smu[f]) * sinv[f], 0.f);
        float b = fmaxf((b2f_hi(u[k]) - smu[f + 1]) * sinv[f + 1], 0.f);
        op[k] = ((unsigned int)f2b(b) << 16) | f2b(a);
    }
    *(uint4*)&out[(size_t)row * ldo + f8] = o;
}

// layer-4 BN(stat-reduce) + ReLU + final 128->2 projection; wave per row, fp32 out
__global__ __launch_bounds__(256) void k_bnfinal(const unsigned short* __restrict__ Y,
                                                 const float* __restrict__ statp,
                                                 const unsigned short* __restrict__ W2,
                                                 const unsigned short* __restrict__ b2v,
                                                 float* __restrict__ out, int n, float invN) {
    __shared__ float smu[128], sinv[128];
    int t = threadIdx.x;
    if (t < 128) {
        float s = 0.f, q = 0.f;
#pragma unroll
        for (int sl = 0; sl < 32; sl++) {
            s += statp[sl * 256 + t];
            q += statp[sl * 256 + 128 + t];
        }
        float mu = s * invN;
        float var = q * invN - mu * mu;
        smu[t] = mu;
        sinv[t] = rsqrtf(var + 1e-5f);
    }
    __syncthreads();
    int wid = t >> 6, lane = t & 63;
    int r = blockIdx.x * 4 + wid;
    if (r >= n) return;
    int f2 = lane * 2;
    unsigned int v = *(const unsigned int*)&Y[(size_t)r * 128 + f2];
    float a = fmaxf((b2f_lo(v) - smu[f2]) * sinv[f2], 0.f);
    float b = fmaxf((b2f_hi(v) - smu[f2 + 1]) * sinv[f2 + 1], 0.f);
    unsigned int w0 = *(const unsigned int*)&W2[f2];
    unsigned int w1 = *(const unsigned int*)&W2[128 + f2];
    float d0 = a * b2f_lo(w0) + b * b2f_hi(w0);
    float d1 = a * b2f_lo(w1) + b * b2f_hi(w1);
    for (int o = 32; o > 0; o >>= 1) {
        d0 += __shfl_down(d0, o, 64);
        d1 += __shfl_down(d1, o, 64);
    }
    if (lane == 0) {
        float2 o2;
        o2.x = d0 + b2f(b2v[0]);
        o2.y = d1 + b2f(b2v[1]);
        *(float2*)&out[(size_t)r * 2] = o2;
    }
}

extern "C" void kernel_launch(void* const* d_in, const int* in_sizes, int n_in,
                              void* d_out, int out_size, void* d_ws, size_t ws_size,
                              hipStream_t stream) {
    const int N = in_sizes[0] / 128;
    const int E = in_sizes[1] / 2;

    const float* x = (const float*)d_in[0];
    const int* ei = (const int*)d_in[1];
    const int* srcp = ei;
    const int* dstp = ei + E;
    float* out = (float*)d_out;

    char* w = (char*)d_ws;
    auto align256 = [](size_t v) { return (v + 255) & ~(size_t)255; };
    size_t o_xcat = 0;
    size_t o_y    = align256(o_xcat + (size_t)N * 256 * 2);
    size_t o_csr  = align256(o_y + (size_t)N * 128 * 2);
    size_t o_rs   = align256(o_csr + (size_t)E * 4);
    size_t o_pos  = align256(o_rs + (size_t)(N + 1) * 4);
    size_t o_inv  = align256(o_pos + (size_t)N * 4);
    size_t o_cnt  = align256(o_inv + (size_t)N * 4);
    size_t o_stat = o_cnt + (size_t)N * 4;            // contiguous with cnt (one memset)
    size_t o_bsum = align256(o_stat + 4 * 8192 * 4);
    size_t o_boff = align256(o_bsum + 1024 * 4);
    size_t o_wbuf = align256(o_boff + 1024 * 4);

    unsigned short* xcat = (unsigned short*)(w + o_xcat);
    unsigned short* y    = (unsigned short*)(w + o_y);
    int* csr = (int*)(w + o_csr);
    int* rs  = (int*)(w + o_rs);
    int* pos = (int*)(w + o_pos);
    float* inv = (float*)(w + o_inv);
    int* cnt = (int*)(w + o_cnt);
    float* stat = (float*)(w + o_stat);
    int* bsum = (int*)(w + o_bsum);
    int* boff = (int*)(w + o_boff);
    unsigned short* wbuf = (unsigned short*)(w + o_wbuf);

    const unsigned short* Wl[3] = {wbuf + 0,      wbuf + 32768, wbuf + 65536};
    const unsigned short* Wr[3] = {wbuf + 16384,  wbuf + 49152, wbuf + 81920};
    const unsigned short* W1b   = wbuf + 98304;
    const unsigned short* bl[3] = {wbuf + 114688, wbuf + 114816, wbuf + 114944};
    const unsigned short* b1b   = wbuf + 115072;
    const unsigned short* W2b   = wbuf + 115200;
    const unsigned short* b2b   = wbuf + 115456;

    WSrc wsrc;
    wsrc.p[0] = (const float*)d_in[2];   // Wl0
    wsrc.p[1] = (const float*)d_in[4];   // Wr0
    wsrc.p[2] = (const float*)d_in[5];   // Wl1
    wsrc.p[3] = (const float*)d_in[7];   // Wr1
    wsrc.p[4] = (const float*)d_in[8];   // Wl2
    wsrc.p[5] = (const float*)d_in[10];  // Wr2
    wsrc.p[6] = (const float*)d_in[11];  // W1
    wsrc.s[0] = (const float*)d_in[3];   // bl0
    wsrc.s[1] = (const float*)d_in[6];   // bl1
    wsrc.s[2] = (const float*)d_in[9];   // bl2
    wsrc.s[3] = (const float*)d_in[12];  // b1
    wsrc.s[4] = (const float*)d_in[13];  // W2
    wsrc.s[5] = (const float*)d_in[14];  // b2

    const int NB = (N + 255) / 256;
    const int nCvtw = (115458 + 255) / 256;
    const int nCount = (E + 255) / 256;
    const int nCopyx = (N * 32 + 255) / 256;

    // zero cnt + stat (contiguous, one memset)
    hipMemsetAsync(w + o_cnt, 0, (size_t)N * 4 + 4 * 8192 * 4, stream);

    k_prologue<<<nCvtw + nCount + nCopyx, 256, 0, stream>>>(wsrc, wbuf, dstp, cnt, E,
                                                            x, xcat, N, nCvtw, nCount);
    k_bsum<<<NB, 256, 0, stream>>>(cnt, bsum, N);
    k_scanb<<<1, 512, 0, stream>>>(bsum, boff, NB);
    k_scanf<<<NB, 256, 0, stream>>>(cnt, boff, rs, pos, inv, N);
    k_fill<<<(E + 255) / 256, 256, 0, stream>>>(srcp, dstp, pos, csr, E);

    const int wg_grid = 512;     // persistent: 2 blocks/CU
    const int agg16_grid = (N + 15) / 16;
    const int wave_grid = (N + 3) / 4;
    const int bnr_grid = (N * 16 + 255) / 256;
    const float invN = 1.0f / (float)N;

    // layer 0
    k_agg<<<agg16_grid, 256, 0, stream>>>(xcat, rs, csr, inv, xcat, N);
    k_wgemm<<<wg_grid, 256, 0, stream>>>(xcat, 256, 0, Wl[0], Wr[0], bl[0], y, stat + 0 * 8192, N, 256);
    // layers 1,2: fused BN+ReLU+agg from raw Y
    for (int i = 1; i < 3; i++) {
        k_aggbn<<<agg16_grid, 256, 0, stream>>>(y, stat + (i - 1) * 8192, rs, csr, inv, xcat, N, invN);
        k_wgemm<<<wg_grid, 256, 0, stream>>>(xcat, 256, 0, Wl[i], Wr[i], bl[i], y, stat + i * 8192, N, 256);
    }
    // MLP stage: BN+ReLU -> xcatR, then K=128 gemm
    k_bnrelu<<<bnr_grid, 256, 0, stream>>>(y, stat + 2 * 8192, xcat + 128, 256, N, invN);
    k_wgemm<<<wg_grid, 256, 0, stream>>>(xcat, 256, 128, W1b, W1b, b1b, y, stat + 3 * 8192, N, 128);
    k_bnfinal<<<wave_grid, 256, 0, stream>>>(y, stat + 3 * 8192, W2b, b2b, out, N, invN);
}